// Round 1
// baseline (1072.847 us; speedup 1.0000x reference)
//
#include <hip/hip_runtime.h>
#include <math.h>

// Problem constants
#define Bn 2
#define Sn 2048
#define Dn 1024
#define Hn 16
#define HDn 64
#define MLPn 4096
#define Mn 4096  // Bn*Sn tokens

typedef float f4 __attribute__((ext_vector_type(4)));
typedef short bfrag __attribute__((ext_vector_type(8)));     // 8 bf16 for MFMA
typedef unsigned int u32x2 __attribute__((ext_vector_type(2)));
typedef unsigned short u16x4 __attribute__((ext_vector_type(4)));

__device__ __forceinline__ unsigned short f2bf(float f) {
  unsigned u = __float_as_uint(f);
  u += 0x7fffu + ((u >> 16) & 1u);   // RNE
  return (unsigned short)(u >> 16);
}
__device__ __forceinline__ float bf2f(unsigned short u) {
  return __uint_as_float(((unsigned)u) << 16);
}
__device__ __forceinline__ f4 load4bf(const unsigned short* p) {
  u32x2 u = *(const u32x2*)p;
  f4 r;
  r[0] = __uint_as_float(u[0] << 16);
  r[1] = __uint_as_float(u[0] & 0xffff0000u);
  r[2] = __uint_as_float(u[1] << 16);
  r[3] = __uint_as_float(u[1] & 0xffff0000u);
  return r;
}
__device__ __forceinline__ void store4bf(unsigned short* p, f4 v) {
  u16x4 o;
  o[0] = f2bf(v[0]); o[1] = f2bf(v[1]); o[2] = f2bf(v[2]); o[3] = f2bf(v[3]);
  *(u16x4*)p = o;
}

#define GLOAD16(gp, lp) __builtin_amdgcn_global_load_lds( \
    (const __attribute__((address_space(1))) void*)(gp),  \
    (__attribute__((address_space(3))) void*)(lp), 16, 0, 0)

// ---------------------------------------------------------------------------
// Weight transpose + fp32->bf16: in [K][N] fp32  ->  out [N][K] bf16
// ---------------------------------------------------------------------------
__global__ void transpose_to_bf16(const float* __restrict__ in,
                                  unsigned short* __restrict__ out,
                                  int K, int N) {
  __shared__ float tile[32][33];
  const int n0 = blockIdx.x * 32;
  const int k0 = blockIdx.y * 32;
  const int tx = threadIdx.x, ty = threadIdx.y;  // (32,8)
  #pragma unroll
  for (int i = 0; i < 32; i += 8)
    tile[ty + i][tx] = in[(size_t)(k0 + ty + i) * N + n0 + tx];
  __syncthreads();
  #pragma unroll
  for (int i = 0; i < 32; i += 8)
    out[(size_t)(n0 + ty + i) * K + k0 + tx] = f2bf(tile[tx][ty + i]);
}

// ---------------------------------------------------------------------------
// LayerNorm over D=1024, fp32 in -> bf16 out. One block per row.
// ---------------------------------------------------------------------------
__global__ __launch_bounds__(256)
void ln_k(const float* __restrict__ x, const float* __restrict__ g,
          const float* __restrict__ bta, unsigned short* __restrict__ out) {
  const int row = blockIdx.x;
  const int tid = threadIdx.x;
  const float* xr = x + (size_t)row * Dn;
  f4 v = ((const f4*)xr)[tid];
  float s  = v[0] + v[1] + v[2] + v[3];
  float s2 = v[0]*v[0] + v[1]*v[1] + v[2]*v[2] + v[3]*v[3];
  #pragma unroll
  for (int off = 32; off > 0; off >>= 1) {
    s  += __shfl_down(s, off);
    s2 += __shfl_down(s2, off);
  }
  __shared__ float red[8];
  if ((tid & 63) == 0) { red[tid >> 6] = s; red[4 + (tid >> 6)] = s2; }
  __syncthreads();
  const float mean = (red[0] + red[1] + red[2] + red[3]) * (1.f / Dn);
  const float var  = (red[4] + red[5] + red[6] + red[7]) * (1.f / Dn) - mean * mean;
  const float inv  = rsqrtf(var + 1e-5f);
  f4 gv = ((const f4*)g)[tid];
  f4 bv = ((const f4*)bta)[tid];
  u16x4 o;
  o[0] = f2bf((v[0] - mean) * inv * gv[0] + bv[0]);
  o[1] = f2bf((v[1] - mean) * inv * gv[1] + bv[1]);
  o[2] = f2bf((v[2] - mean) * inv * gv[2] + bv[2]);
  o[3] = f2bf((v[3] - mean) * inv * gv[3] + bv[3]);
  ((u16x4*)(out + (size_t)row * Dn))[tid] = o;
}

// ---------------------------------------------------------------------------
// bf16 MFMA GEMM, m97 structure: C[M][N] = A[M][K] * Bt[N][K]^T (+ epilogue)
// 128x128 tile, BK=32, 4 waves (2x2), 4x4 16x16 fragments per wave.
// MODE 0: bf16 out = elu(acc+bias)+1        (q,k)
// MODE 1: bf16 out = acc+bias               (v)
// MODE 2: f32  out = acc+bias+lambd*res     (attn_out + skip -> xmid)
// MODE 3: bf16 out = gelu_tanh(acc+bias)    (mlp hidden)
// MODE 4: f32  out = acc+bias+res           (final)
// ---------------------------------------------------------------------------
template<int MODE>
__global__ __launch_bounds__(256)
void gemm_bt(const unsigned short* __restrict__ A,
             const unsigned short* __restrict__ Bt,
             int Mdim, int Ndim, int Kdim,
             const float* __restrict__ bias,
             const float* __restrict__ res,
             const float* __restrict__ lambd,
             float* __restrict__ outf,
             unsigned short* __restrict__ outb) {
  __shared__ unsigned short As[128 * 32];
  __shared__ unsigned short Bs[128 * 32];
  const int tid  = threadIdx.x;
  const int lane = tid & 63;
  const int wid  = tid >> 6;
  const int wr   = wid >> 1, wc = wid & 1;
  const int bm = blockIdx.x, bn = blockIdx.y;

  f4 acc[4][4] = {};

  // staging geometry: each global_load_lds instr moves 1024B = 16 rows x 64B
  const int lrow = lane >> 2;        // 0..15
  const int lcol = (lane & 3) * 8;   // element col within BK
  const unsigned short* Ag = A + (size_t)(bm * 128 + lrow) * Kdim + lcol;
  const unsigned short* Bg = Bt + (size_t)(bn * 128 + lrow) * Kdim + lcol;

  const int arow = wr * 64 + (lane & 15);
  const int brow = wc * 64 + (lane & 15);
  const int koff = (lane >> 4) * 8;

  for (int kt = 0; kt < Kdim; kt += 32) {
    __syncthreads();  // previous iteration's LDS reads done
    #pragma unroll
    for (int i = 0; i < 2; ++i) {
      const int rbase = (wid * 2 + i) * 16;
      GLOAD16(Ag + (size_t)rbase * Kdim + kt, As + rbase * 32);
      GLOAD16(Bg + (size_t)rbase * Kdim + kt, Bs + rbase * 32);
    }
    __syncthreads();  // drains vmcnt -> LDS tile visible

    bfrag af[4], bfr[4];
    #pragma unroll
    for (int mi = 0; mi < 4; ++mi)
      af[mi] = *(const bfrag*)(As + (arow + mi * 16) * 32 + koff);
    #pragma unroll
    for (int ni = 0; ni < 4; ++ni)
      bfr[ni] = *(const bfrag*)(Bs + (brow + ni * 16) * 32 + koff);
    #pragma unroll
    for (int mi = 0; mi < 4; ++mi)
      #pragma unroll
      for (int ni = 0; ni < 4; ++ni)
        acc[mi][ni] = __builtin_amdgcn_mfma_f32_16x16x32_bf16(
            af[mi], bfr[ni], acc[mi][ni], 0, 0, 0);
  }

  // epilogue
  const int r0 = bm * 128 + wr * 64 + ((lane >> 4) << 2);
  const int c0 = bn * 128 + wc * 64 + (lane & 15);
  const float lam = (MODE == 2) ? lambd[0] : 0.f;
  #pragma unroll
  for (int mi = 0; mi < 4; ++mi) {
    #pragma unroll
    for (int ni = 0; ni < 4; ++ni) {
      const int col = c0 + ni * 16;
      const float bcol = bias[col];
      #pragma unroll
      for (int r = 0; r < 4; ++r) {
        const int row = r0 + mi * 16 + r;
        const size_t idx = (size_t)row * Ndim + col;
        float v = acc[mi][ni][r] + bcol;
        if (MODE == 0) {
          v = (v > 0.f) ? (v + 1.f) : __expf(v);
          outb[idx] = f2bf(v);
        } else if (MODE == 1) {
          outb[idx] = f2bf(v);
        } else if (MODE == 2) {
          outf[idx] = v + lam * res[idx];
        } else if (MODE == 3) {
          const float t = 0.7978845608028654f * (v + 0.044715f * v * v * v);
          outb[idx] = f2bf(0.5f * v * (1.f + tanhf(t)));
        } else {
          outf[idx] = v + res[idx];
        }
      }
    }
  }
}

// ---------------------------------------------------------------------------
// Linear attention, chunked (chunk = 256 rows), fp32 math.
// Pass A: per (chunk, b, h): KV_c[64][64] = sum_j k_j (x) v_j ; ksum_c[64]
// ---------------------------------------------------------------------------
#define NCHUNK 8  // Sn/256
__global__ __launch_bounds__(256)
void attn_stats_k(const unsigned short* __restrict__ qk,
                  const unsigned short* __restrict__ vv,
                  float* __restrict__ stats) {
  const int c = blockIdx.x, bh = blockIdx.y;
  const int b = bh >> 4, h = bh & 15;
  const int tid = threadIdx.x;
  __shared__ float ks[64][64];
  __shared__ float vs[64][64];
  const int dm = tid >> 2;          // 0..63
  const int g0 = tid & 3;           // f4-group base: cols g0*16..
  f4 acc[4] = {};
  float ksum = 0.f;
  const size_t rowbase = (size_t)b * Sn + (size_t)c * 256;

  for (int sub = 0; sub < 4; ++sub) {
    __syncthreads();
    for (int li = tid; li < 1024; li += 256) {  // 64 rows * 16 f4-groups
      const int j = li >> 4;
      const int d4 = (li & 15) << 2;
      const size_t grow = rowbase + sub * 64 + j;
      *(f4*)&ks[j][d4] = load4bf(qk + grow * 2048 + 1024 + h * 64 + d4);
      *(f4*)&vs[j][d4] = load4bf(vv + grow * 1024 + h * 64 + d4);
    }
    __syncthreads();
    for (int j = 0; j < 64; ++j) {
      const float s = ks[j][dm];
      const f4* vrow = (const f4*)vs[j];
      #pragma unroll
      for (int g = 0; g < 4; ++g) acc[g] += s * vrow[g0 * 4 + g];
    }
    if (tid < 64) {
      for (int j = 0; j < 64; ++j) ksum += ks[j][tid];
    }
  }
  float* op = stats + ((size_t)bh * NCHUNK + c) * 4160 + dm * 64 + g0 * 16;
  #pragma unroll
  for (int g = 0; g < 4; ++g) *(f4*)(op + g * 4) = acc[g];
  if (tid < 64) stats[((size_t)bh * NCHUNK + c) * 4160 + 4096 + tid] = ksum;
}

// Pass B: exclusive scan over chunks per (b,h)
__global__ __launch_bounds__(256)
void attn_scan_k(const float* __restrict__ stats, float* __restrict__ prefix) {
  const int bh = blockIdx.x;
  const int tid = threadIdx.x;
  for (int idx = tid; idx < 4160; idx += 256) {
    float r = 0.f;
    for (int c = 0; c < NCHUNK; ++c) {
      prefix[((size_t)bh * NCHUNK + c) * 4160 + idx] = r;
      r += stats[((size_t)bh * NCHUNK + c) * 4160 + idx];
    }
  }
}

// Pass C: per (chunk, b, h): one thread per row.
__global__ __launch_bounds__(256)
void attn_out_k(const unsigned short* __restrict__ qk,
                const unsigned short* __restrict__ vv,
                const float* __restrict__ prefix,
                unsigned short* __restrict__ ctx) {
  const int c = blockIdx.x, bh = blockIdx.y;
  const int b = bh >> 4, h = bh & 15;
  const int tid = threadIdx.x;
  const int w = tid >> 6;
  const int i = tid;  // row within chunk

  __shared__ float ks[64][64];
  __shared__ float vs[64][64];
  __shared__ float kvp[64 * 64];
  __shared__ float ksp[64];

  const size_t rowbase = (size_t)b * Sn + (size_t)c * 256;
  const unsigned short* qp = qk + (rowbase + i) * 2048 + h * 64;

  f4 qv[16];
  #pragma unroll
  for (int g = 0; g < 16; ++g) qv[g] = load4bf(qp + g * 4);

  const float* pf = prefix + ((size_t)bh * NCHUNK + c) * 4160;
  for (int idx = tid; idx < 4096; idx += 256) kvp[idx] = pf[idx];
  if (tid < 64) ksp[tid] = pf[4096 + tid];
  __syncthreads();

  f4 outv[16];
  #pragma unroll
  for (int g = 0; g < 16; ++g) outv[g] = (f4){0.f, 0.f, 0.f, 0.f};
  float den = 0.f;

  // inter-chunk: out += q @ KV_prefix ; den += q . ksum_prefix
  // (q re-read from L1/L2 to keep d-loop runtime-indexed without spilling qv)
  for (int d = 0; d < 64; ++d) {
    const float qd = bf2f(qp[d]);
    den += qd * ksp[d];
    const f4* kvrow = (const f4*)(kvp + d * 64);
    #pragma unroll
    for (int g = 0; g < 16; ++g) outv[g] += qd * kvrow[g];
  }

  // intra-chunk, causal
  for (int sub = 0; sub < 4; ++sub) {
    __syncthreads();
    for (int li = tid; li < 1024; li += 256) {
      const int j = li >> 4;
      const int d4 = (li & 15) << 2;
      const size_t grow = rowbase + sub * 64 + j;
      *(f4*)&ks[j][d4] = load4bf(qk + grow * 2048 + 1024 + h * 64 + d4);
      *(f4*)&vs[j][d4] = load4bf(vv + grow * 1024 + h * 64 + d4);
    }
    __syncthreads();
    if (w >= sub) {
      const int jg0 = sub * 64;
      const bool diag = (sub == w);
      for (int jl = 0; jl < 64; ++jl) {
        const f4* krow = (const f4*)ks[jl];
        f4 sa = (f4){0.f, 0.f, 0.f, 0.f};
        #pragma unroll
        for (int g = 0; g < 16; ++g) sa += qv[g] * krow[g];
        float s = sa[0] + sa[1] + sa[2] + sa[3];
        if (diag && (jg0 + jl) > i) s = 0.f;
        den += s;
        const f4* vrow = (const f4*)vs[jl];
        #pragma unroll
        for (int g = 0; g < 16; ++g) outv[g] += s * vrow[g];
      }
    }
  }

  const float n = 1.f / den;
  unsigned short* cp = ctx + (rowbase + i) * 1024 + h * 64;
  #pragma unroll
  for (int g = 0; g < 16; ++g) store4bf(cp + g * 4, outv[g] * n);
}

// ---------------------------------------------------------------------------
extern "C" void kernel_launch(void* const* d_in, const int* in_sizes, int n_in,
                              void* d_out, int out_size, void* d_ws, size_t ws_size,
                              hipStream_t stream) {
  const float* x     = (const float*)d_in[0];
  const float* lambd = (const float*)d_in[1];
  const float* ln_g  = (const float*)d_in[2];
  const float* ln_b  = (const float*)d_in[3];
  const float* Wqk   = (const float*)d_in[4];
  const float* bqk   = (const float*)d_in[5];
  const float* Wv    = (const float*)d_in[6];
  const float* bv    = (const float*)d_in[7];
  const float* Wo    = (const float*)d_in[8];
  const float* bo    = (const float*)d_in[9];
  const float* W1    = (const float*)d_in[10];
  const float* b1    = (const float*)d_in[11];
  const float* W2    = (const float*)d_in[12];
  const float* b2    = (const float*)d_in[13];
  float* out = (float*)d_out;

  char* ws = (char*)d_ws;
  size_t off = 0;
  auto alloc = [&](size_t bytes) -> void* {
    void* p = ws + off;
    off += (bytes + 255) & ~(size_t)255;
    return p;
  };
  unsigned short* wqk_t = (unsigned short*)alloc((size_t)2048 * 1024 * 2);
  unsigned short* wv_t  = (unsigned short*)alloc((size_t)1024 * 1024 * 2);
  unsigned short* wo_t  = (unsigned short*)alloc((size_t)1024 * 1024 * 2);
  unsigned short* w1_t  = (unsigned short*)alloc((size_t)4096 * 1024 * 2);
  unsigned short* w2_t  = (unsigned short*)alloc((size_t)1024 * 4096 * 2);
  unsigned short* xn    = (unsigned short*)alloc((size_t)Mn * Dn * 2);     // also y
  unsigned short* qkb   = (unsigned short*)alloc((size_t)Mn * 2048 * 2);
  unsigned short* vb    = (unsigned short*)alloc((size_t)Mn * Dn * 2);
  unsigned short* ctxb  = (unsigned short*)alloc((size_t)Mn * Dn * 2);
  float*          xmid  = (float*)alloc((size_t)Mn * Dn * 4);
  float*          stats = (float*)alloc((size_t)32 * NCHUNK * 4160 * 4);
  float*          prefx = (float*)alloc((size_t)32 * NCHUNK * 4160 * 4);
  unsigned short* hb    = qkb;  // alias: qk/v/ctx (32MB) dead before MLP1 writes h

  dim3 tb(32, 8);
  transpose_to_bf16<<<dim3(64, 32),  tb, 0, stream>>>(Wqk, wqk_t, 1024, 2048);
  transpose_to_bf16<<<dim3(32, 32),  tb, 0, stream>>>(Wv,  wv_t,  1024, 1024);
  transpose_to_bf16<<<dim3(32, 32),  tb, 0, stream>>>(Wo,  wo_t,  1024, 1024);
  transpose_to_bf16<<<dim3(128, 32), tb, 0, stream>>>(W1,  w1_t,  1024, 4096);
  transpose_to_bf16<<<dim3(32, 128), tb, 0, stream>>>(W2,  w2_t,  4096, 1024);

  ln_k<<<Mn, 256, 0, stream>>>(x, ln_g, ln_b, xn);

  gemm_bt<0><<<dim3(32, 16), 256, 0, stream>>>(xn, wqk_t, Mn, 2048, 1024,
                                               bqk, nullptr, nullptr, nullptr, qkb);
  gemm_bt<1><<<dim3(32, 8), 256, 0, stream>>>(xn, wv_t, Mn, 1024, 1024,
                                              bv, nullptr, nullptr, nullptr, vb);

  attn_stats_k<<<dim3(NCHUNK, 32), 256, 0, stream>>>(qkb, vb, stats);
  attn_scan_k<<<32, 256, 0, stream>>>(stats, prefx);
  attn_out_k<<<dim3(NCHUNK, 32), 256, 0, stream>>>(qkb, vb, prefx, ctxb);

  gemm_bt<2><<<dim3(32, 8), 256, 0, stream>>>(ctxb, wo_t, Mn, 1024, 1024,
                                              bo, x, lambd, xmid, nullptr);

  ln_k<<<Mn, 256, 0, stream>>>(xmid, ln_g, ln_b, xn);  // xn now holds y

  gemm_bt<3><<<dim3(32, 32), 256, 0, stream>>>(xn, w1_t, Mn, 4096, 1024,
                                               b1, nullptr, nullptr, nullptr, hb);
  gemm_bt<4><<<dim3(32, 8), 256, 0, stream>>>(hb, w2_t, Mn, 1024, 4096,
                                              b2, xmid, nullptr, out, nullptr);
}